// Round 16
// baseline (798.920 us; speedup 1.0000x reference)
//
#include <hip/hip_runtime.h>

#define B_   32
#define T_   512
#define D_   256
#define C_   64
#define R_   4
#define RD_  64
#define OUT_ 256

// ---------------------------------------------------------------------------
__device__ __forceinline__ void bar_lds() {
  asm volatile("s_waitcnt lgkmcnt(0)" ::: "memory");
  __builtin_amdgcn_s_barrier();
  asm volatile("" ::: "memory");
}

// ---- DPP-based wave reductions (VALU pipe) ---------------------------------
template <int CTRL>
__device__ __forceinline__ float dpp_add(float v) {
  int s = __builtin_amdgcn_update_dpp(0, __float_as_int(v), CTRL, 0xF, 0xF, true);
  return v + __int_as_float(s);
}
__device__ __forceinline__ float row16_sum(float v) {
  v = dpp_add<0xB1>(v);   // quad_perm [1,0,3,2]
  v = dpp_add<0x4E>(v);   // quad_perm [2,3,0,1]
  v = dpp_add<0x141>(v);  // row_half_mirror
  v = dpp_add<0x140>(v);  // row_mirror
  return v;
}
__device__ __forceinline__ float rlane(float v, int l) {
  return __int_as_float(__builtin_amdgcn_readlane(__float_as_int(v), l));
}
__device__ __forceinline__ int rlane_i(int v, int l) {
  return __builtin_amdgcn_readlane(v, l);
}
__device__ __forceinline__ float wave_sum_dpp(float v) {
  const float r = row16_sum(v);
  return (rlane(r, 0) + rlane(r, 16)) + (rlane(r, 32) + rlane(r, 48));
}

// ---------------------------------------------------------------------------
// Xpre = X @ W   (16384 x 256) @ (256 x 256), f32
__global__ __launch_bounds__(256) void xpre_kernel(const float* __restrict__ X,
                                                   const float* __restrict__ W,
                                                   float* __restrict__ XP) {
  __shared__ __align__(16) float xs[32][D_];
  const int j = threadIdx.x;
  const int row0 = blockIdx.x * 32;
  for (int k = 0; k < 32; ++k)
    xs[k][j] = X[(size_t)(row0 + k) * D_ + j];
  __syncthreads();
  float acc[32];
#pragma unroll
  for (int k = 0; k < 32; ++k) acc[k] = 0.f;
  for (int d4 = 0; d4 < D_ / 4; ++d4) {
    const float w0 = W[(d4 * 4 + 0) * OUT_ + j];
    const float w1 = W[(d4 * 4 + 1) * OUT_ + j];
    const float w2 = W[(d4 * 4 + 2) * OUT_ + j];
    const float w3 = W[(d4 * 4 + 3) * OUT_ + j];
#pragma unroll
    for (int k = 0; k < 32; ++k) {
      const float4 x4 = *(const float4*)&xs[k][d4 * 4];
      acc[k] = fmaf(x4.x, w0, fmaf(x4.y, w1, fmaf(x4.z, w2, fmaf(x4.w, w3, acc[k]))));
    }
  }
  for (int k = 0; k < 32; ++k)
    XP[(size_t)(row0 + k) * OUT_ + j] = acc[k];
}

// ---------------------------------------------------------------------------
// attnK: attention weights + aggs for ALL (b,t). One wave per (b,t).
// walG[bt*256 + r*64 + c] = (ri[c]==r ? alpha[c] : 0).
__global__ __launch_bounds__(256) void attnK(const float* __restrict__ X,
                                             const int* __restrict__ Ri,
                                             const int* __restrict__ Ei,
                                             const float* __restrict__ Watt,
                                             float* __restrict__ walG,
                                             float* __restrict__ aggs) {
  const int wv = threadIdx.x >> 6;
  const int lane = threadIdx.x & 63;
  const size_t bt = (size_t)blockIdx.x * 4 + wv;
  const int r4 = lane >> 4, seg = lane & 15;

  float y = 0.f;
#pragma unroll
  for (int q = 0; q < 4; ++q) {
    const float4 wt = *(const float4*)&Watt[(r4 << 8) + (seg << 4) + (q << 2)];
    const float4 xv = *(const float4*)&X[bt * D_ + (seg << 4) + (q << 2)];
    y = fmaf(xv.x, wt.x, y);
    y = fmaf(xv.y, wt.y, y);
    y = fmaf(xv.z, wt.z, y);
    y = fmaf(xv.w, wt.w, y);
  }
  y = row16_sum(y);
  const float y0 = rlane(y, 0), y1 = rlane(y, 16);
  const float y2 = rlane(y, 32), y3 = rlane(y, 48);
  const int ric = Ri[bt * C_ + lane];
  const float eic = (float)Ei[bt * C_ + lane];
  float yv = (ric & 1) ? y1 : y0;
  const float yw = (ric & 1) ? y3 : y2;
  yv = (ric & 2) ? yw : yv;
  const float am = __expf(yv) * eic;  // EPS=1e-100 underflows in f32
  const float tot = wave_sum_dpp(am);
  const float alpha = __fdividef(am, tot);

  const float w0 = (ric == 0) ? alpha : 0.f;
  const float w1 = (ric == 1) ? alpha : 0.f;
  const float w2 = (ric == 2) ? alpha : 0.f;
  const float w3 = (ric == 3) ? alpha : 0.f;
  walG[bt * 256 + 0 * C_ + lane] = w0;
  walG[bt * 256 + 1 * C_ + lane] = w1;
  walG[bt * 256 + 2 * C_ + lane] = w2;
  walG[bt * 256 + 3 * C_ + lane] = w3;
  const float s0 = wave_sum_dpp(w0);
  const float s1 = wave_sum_dpp(w1);
  const float s2 = wave_sum_dpp(w2);
  const float s3 = wave_sum_dpp(w3);
  if (lane == 0) {
    float4 v = {s0, s1, s2, s3};
    *(float4*)&aggs[bt * R_] = v;
  }
}

// ---------------------------------------------------------------------------
// gruA: recurrent core. 32 blocks x 1024 threads (16 waves, 4 waves/SIMD).
// 2 barriers/step via the masked-GEMV decomposition:
//   prev(k+1) = wal(k+1)*(1-eo(k))*mt(k-1)  [computed during step k, off-path]
//             + coef(k)*hnew(k)             [4x4 input-only coef, 4-FMA corr]
// P1(k): mt-update(hnew(k-1)) | masked-GEMV(k+1) partials -> shp2[nxt] |
//        prev(k) assembly (shp2[cur] + coef*hnew corr) | h2h partials |
//        copy-span(k-1) on waves 8-15
// P2(k): gates -> hnew(k) (waves 0-3) | coef(k) DPP sums (waves 4-7) |
//        parity prefetch reloads (all)
__global__ __launch_bounds__(1024, 4) void gruA(
    const int* __restrict__ M, const int* __restrict__ Eo,
    const int* __restrict__ Ro, const float* __restrict__ U,
    const float* __restrict__ Bv, const float* __restrict__ XP,
    const float* __restrict__ walG, float* __restrict__ outs) {
  __shared__ __align__(16) float shp2[2][16][256];  // dbuf masked prev partials
  __shared__ __align__(16) float pBred[16][256];    // [wave][j] h2h partials
  __shared__ __align__(16) float shprev[OUT_];      // prev[j]
  __shared__ __align__(16) float sh_hnew[OUT_];
  __shared__ float sh_coef[16];                     // coef[r*4+r2]
  __shared__ int sh_tl[T_];
  __shared__ int sh_nT;

  const int tid = threadIdx.x;
  const int lane = tid & 63;
  const int w = tid >> 6;      // 0..15
  const int b = blockIdx.x;
  const size_t bt0 = (size_t)b * T_;

  // U slice: ureg[jj*16+i] = U[16w+i][jj*64+lane]  (K-range 16 per wave)
  float ureg[64];
#pragma unroll
  for (int jj = 0; jj < 4; ++jj)
#pragma unroll
    for (int i = 0; i < 16; ++i)
      ureg[(jj << 4) + i] = U[(size_t)((w << 4) + i) * OUT_ + (jj << 6) + lane];
  const float breg = Bv[tid & 255];  // used by waves 0-3

  // m state: mtreg[q] = mt[4w+q][lane], init 0
  float mtreg[4];
#pragma unroll
  for (int q = 0; q < 4; ++q) mtreg[q] = 0.f;

  // tlist: indices of m=1 steps (wave 0, ballot prefix scan)
  if (tid < 64) {
    int base = 0;
    for (int ch = 0; ch < 8; ++ch) {
      const int mv = M[bt0 + (ch << 6) + lane];
      const unsigned long long mask = __ballot(mv != 0);
      if (mv) {
        const unsigned long long lt = ((lane == 63) ? ~0ull : ((1ull << (lane + 1)) - 1)) >> 1;
        sh_tl[base + __popcll(mask & lt)] = (ch << 6) + lane;
      }
      base += __popcll(mask);
    }
    if (lane == 0) sh_nT = base;
  }
  // zero state buffers used by iteration 0
  for (int i = tid; i < 16 * 256; i += 1024) ((float*)shp2[0])[i] = 0.f;
  if (tid < 256) sh_hnew[tid] = 0.f;
  if (tid < 16) sh_coef[tid] = 0.f;
  __syncthreads();
  const int nT = sh_nT;

  // zero-prefix: outs rows [0, t_0) are h0 = 0 (all rows if nT == 0)
  {
    const int t0 = (nT > 0) ? sh_tl[0] : T_;
    const int j = tid & 255;
    for (int t = tid >> 8; t < t0; t += 4)
      outs[(bt0 + t) * OUT_ + j] = 0.f;
  }
  if (nT == 0) return;

  // layouts:
  //  walS : wal[r=lane&3][c = 4w + (lane>>4)]  (readlane at (q<<4)+r) — wal(t_{k+1})
  //  xpS  : XP[., tid]                 (waves 0-3) — XP(t_k)
  //  reS  : Ro|(Eo<<8) at c=4w+(lane&3) (readlane at q) — masks(t_k)
  //  walC : wal rows 0-3 at c=lane     (waves 4-7 coef) — wal(t_{k+1})
  //  reF  : Ro|(Eo<<8) at c=lane       (coef) — masks(t_k)
  const int cwal = (w << 2) + (lane >> 4);
  const int rwal = lane & 3;
  const int croeo = (w << 2) + (lane & 3);

  auto loadWalS = [&](int t) { return walG[(bt0 + t) * 256 + (rwal << 6) + cwal]; };
  auto loadRe = [&](int t) { return Ro[(bt0 + t) * C_ + croeo] | (Eo[(bt0 + t) * C_ + croeo] << 8); };
  auto loadReF = [&](int t) { return Ro[(bt0 + t) * C_ + lane] | (Eo[(bt0 + t) * C_ + lane] << 8); };
  auto loadWalC = [&](int t) {
    float4 v;
    v.x = walG[(bt0 + t) * 256 + 0 * 64 + lane];
    v.y = walG[(bt0 + t) * 256 + 1 * 64 + lane];
    v.z = walG[(bt0 + t) * 256 + 2 * 64 + lane];
    v.w = walG[(bt0 + t) * 256 + 3 * 64 + lane];
    return v;
  };

  const int tl0 = sh_tl[0];
  const int tl1 = sh_tl[(nT > 1) ? 1 : 0];
  const int tl2 = sh_tl[(nT > 2) ? 2 : (nT - 1)];
  float walS0 = loadWalS(tl1), walS1 = loadWalS(tl2);
  float xpS0 = (w < 4) ? XP[(bt0 + tl0) * 256 + tid] : 0.f;
  float xpS1 = (w < 4) ? XP[(bt0 + tl1) * 256 + tid] : 0.f;
  int reS0 = loadRe(tl0), reS1 = loadRe(tl1);
  float4 walC0 = loadWalC(tl1), walC1 = loadWalC(tl2);
  int reF0 = loadReF(tl0), reF1 = loadReF(tl1);
  int rePrev = 0;  // no mt update before step 0

  auto do_step = [&](int k, float& walS, float& xpS, int& reS, float4& walC,
                     int& reF) {
    const int cur = k & 1, nxt = cur ^ 1;
    const int tk = sh_tl[k];
    const size_t bt = bt0 + tk;

    // ======== P1 ========
    // (a) mt update with hnew(k-1), masks(t_{k-1}) (rePrev; =0 at k=0)
    {
      const float h0 = sh_hnew[lane];
      const float h1 = sh_hnew[64 + lane];
      const float h2 = sh_hnew[128 + lane];
      const float h3 = sh_hnew[192 + lane];
#pragma unroll
      for (int q = 0; q < 4; ++q) {
        const int re = rlane_i(rePrev, q);
        const int ro = re & 0xFF;
        const float ha = (ro & 1) ? h1 : h0;
        const float hb = (ro & 1) ? h3 : h2;
        const float hs = (ro & 2) ? hb : ha;
        mtreg[q] = (re & 0x100) ? hs : mtreg[q];
      }
    }
    // (b) masked-GEMV partials for prev(k+1): wal(k+1)*(1-eo(k))*mt(k-1)
    {
      float a0 = 0.f, a1 = 0.f, a2 = 0.f, a3 = 0.f;
#pragma unroll
      for (int q = 0; q < 4; ++q) {
        const int re = rlane_i(reS, q);  // masks(t_k)
        const float mq = (re & 0x100) ? 0.f : mtreg[q];
        a0 = fmaf(rlane(walS, (q << 4) + 0), mq, a0);
        a1 = fmaf(rlane(walS, (q << 4) + 1), mq, a1);
        a2 = fmaf(rlane(walS, (q << 4) + 2), mq, a2);
        a3 = fmaf(rlane(walS, (q << 4) + 3), mq, a3);
      }
      shp2[nxt][w][0 * 64 + lane] = a0;
      shp2[nxt][w][1 * 64 + lane] = a1;
      shp2[nxt][w][2 * 64 + lane] = a2;
      shp2[nxt][w][3 * 64 + lane] = a3;
    }
    // (c) prev(k) assembly: masked partials + coef(k-1)*hnew(k-1) correction
    const int kidx = (w << 4) + (lane & 15);
    const int rI = w >> 2, d = kidx & 63;
    float px = 0.f;
#pragma unroll
    for (int sw = 0; sw < 16; sw += 4) {
      const float t0 = shp2[cur][sw + 0][kidx], t1 = shp2[cur][sw + 1][kidx];
      const float t2 = shp2[cur][sw + 2][kidx], t3 = shp2[cur][sw + 3][kidx];
      px += (t0 + t1) + (t2 + t3);
    }
    {
      const float c0 = sh_coef[(rI << 2) + 0];
      const float c1 = sh_coef[(rI << 2) + 1];
      const float c2 = sh_coef[(rI << 2) + 2];
      const float c3 = sh_coef[(rI << 2) + 3];
      px = fmaf(c0, sh_hnew[d], px);
      px = fmaf(c1, sh_hnew[64 + d], px);
      px = fmaf(c2, sh_hnew[128 + d], px);
      px = fmaf(c3, sh_hnew[192 + d], px);
    }
    if (lane < 16) shprev[kidx] = px;
    // (d) h2h partials (K-split: 16 RL : 64 FMA)
    {
      float p0 = 0.f, p1 = 0.f, p2 = 0.f, p3 = 0.f;
#pragma unroll
      for (int i = 0; i < 16; ++i) {
        const float pk = rlane(px, i);  // prev[16w + i], wave-uniform
        p0 = fmaf(pk, ureg[i], p0);
        p1 = fmaf(pk, ureg[16 + i], p1);
        p2 = fmaf(pk, ureg[32 + i], p2);
        p3 = fmaf(pk, ureg[48 + i], p3);
      }
      pBred[w][0 * 64 + lane] = p0;
      pBred[w][1 * 64 + lane] = p1;
      pBred[w][2 * 64 + lane] = p2;
      pBred[w][3 * 64 + lane] = p3;
    }
    // (e) copy-span rows (t_{k-1}, t_k) with hnew(k-1) on waves 8-15
    if (w >= 8 && k > 0) {
      const int idx = tid - 512;
      const int rr = idx >> 8;
      const int j = idx & 255;
      const int tprev = sh_tl[k - 1];
      const float hv = sh_hnew[j];
      for (int t = tprev + 1 + rr; t < tk; t += 2)
        outs[(bt0 + t) * OUT_ + j] = hv;
    }
    bar_lds();

    // ======== P2 ========
    if (w < 4) {
      float h2h = 0.f;
#pragma unroll
      for (int kw = 0; kw < 16; kw += 4) {
        const float t0 = pBred[kw + 0][tid], t1 = pBred[kw + 1][tid];
        const float t2 = pBred[kw + 2][tid], t3 = pBred[kw + 3][tid];
        h2h += (t0 + t1) + (t2 + t3);
      }
      const float pOwn = shprev[tid];
      const float g1 = xpS + h2h + breg;
      const float rg = 1.f / (1.f + __expf(-g1));
      const float targ = xpS + rg * h2h + breg;
      const float e2 = __expf(2.f * targ);
      const float ht = 1.f - 2.f / (e2 + 1.f);  // tanh
      const float hn = (1.f - rg) * pOwn + rg * ht;
      sh_hnew[tid] = hn;
      outs[bt * OUT_ + tid] = hn;
    } else if (w < 8) {
      // coef(k)[r][w-4] = sum_c wal(t_{k+1})[r][c]*eo(t_k)[c]*(ro(t_k)[c]==w-4)
      const int r2 = w - 4;
      const float mask =
          (((reF >> 8) & 1) && ((reF & 0xFF) == r2)) ? 1.f : 0.f;
      const float s0 = wave_sum_dpp(walC.x * mask);
      const float s1 = wave_sum_dpp(walC.y * mask);
      const float s2 = wave_sum_dpp(walC.z * mask);
      const float s3 = wave_sum_dpp(walC.w * mask);
      if (lane == 0) {
        sh_coef[0 * 4 + r2] = s0;
        sh_coef[1 * 4 + r2] = s1;
        sh_coef[2 * 4 + r2] = s2;
        sh_coef[3 * 4 + r2] = s3;
      }
    }
    rePrev = reS;  // carry masks(t_k) into (a) of step k+1
    {
      const int k2 = (k + 2 < nT) ? k + 2 : nT - 1;
      const int k3 = (k + 3 < nT) ? k + 3 : nT - 1;
      const int t2v = sh_tl[k2], t3v = sh_tl[k3];
      walS = loadWalS(t3v);
      if (w < 4) xpS = XP[(bt0 + t2v) * 256 + tid];
      reS = loadRe(t2v);
      walC = loadWalC(t3v);
      reF = loadReF(t2v);
    }
    bar_lds();
  };

  for (int k = 0; k < nT; k += 2) {
    do_step(k, walS0, xpS0, reS0, walC0, reF0);
    if (k + 1 < nT)
      do_step(k + 1, walS1, xpS1, reS1, walC1, reF1);
  }

  // epilogue: copy-span rows (t_{nT-1}, T) with hnew(nT-1)
  {
    const int tlast = sh_tl[nT - 1];
    const int j = tid & 255;
    const float hv = sh_hnew[j];
    for (int t = tlast + 1 + (tid >> 8); t < T_; t += 4)
      outs[(bt0 + t) * OUT_ + j] = hv;
  }
}

// ---------------------------------------------------------------------------
// memsB: mems[b,t,c,:] = outs-history(tau)[ro(tau,c)*64+:], tau = last step
// <= t with M&Eo, else 0. Rows at M=1 steps hold true hnew (gruA). One block
// per (b,c).
__global__ __launch_bounds__(512) void memsB(const int* __restrict__ M,
                                             const int* __restrict__ Eo,
                                             const int* __restrict__ Ro,
                                             const float* __restrict__ hbuf,
                                             float* __restrict__ mems) {
  __shared__ int lastA[T_];
  const int tid = threadIdx.x;
  const int b = blockIdx.x >> 6;
  const int c = blockIdx.x & 63;
  const size_t bt0 = (size_t)b * T_;
  {
    const int upd = M[bt0 + tid] & Eo[(bt0 + tid) * C_ + c];
    lastA[tid] = upd ? tid : -1;
  }
  __syncthreads();
  for (int off = 1; off < T_; off <<= 1) {
    const int u = (tid >= off) ? lastA[tid - off] : -1;
    const int v = lastA[tid];
    __syncthreads();
    lastA[tid] = (u > v) ? u : v;
    __syncthreads();
  }
  const int d = tid & 63;
  const int t8 = tid >> 6;
  for (int tt = 0; tt < 64; ++tt) {
    const int t = (tt << 3) + t8;
    const int tau = lastA[t];
    float v = 0.f;
    if (tau >= 0) {
      const int rc = Ro[(bt0 + tau) * C_ + c];
      v = hbuf[(bt0 + tau) * OUT_ + (rc << 6) + d];
    }
    mems[((bt0 + t) * C_ + c) * RD_ + d] = v;
  }
}

// ---------------------------------------------------------------------------
extern "C" void kernel_launch(void* const* d_in, const int* in_sizes, int n_in,
                              void* d_out, int out_size, void* d_ws, size_t ws_size,
                              hipStream_t stream) {
  const float* X = (const float*)d_in[0];
  const int* M = (const int*)d_in[1];
  const int* Ei = (const int*)d_in[2];
  const int* Eo = (const int*)d_in[3];
  const int* Ri = (const int*)d_in[4];
  const int* Ro = (const int*)d_in[5];
  const float* W = (const float*)d_in[6];
  const float* U = (const float*)d_in[7];
  const float* Bv = (const float*)d_in[8];
  const float* Watt = (const float*)d_in[9];

  float* outs = (float*)d_out;
  float* mems = outs + (size_t)B_ * T_ * OUT_;
  float* aggs = mems + (size_t)B_ * T_ * C_ * RD_;
  float* XP = (float*)d_ws;   // 16.8 MB scratch
  float* walG = mems;         // alpha scratch aliases mems (memsB overwrites)

  xpre_kernel<<<dim3(B_ * T_ / 32), dim3(256), 0, stream>>>(X, W, XP);
  attnK<<<dim3(B_ * T_ / 4), dim3(256), 0, stream>>>(X, Ri, Ei, Watt, walG, aggs);
  gruA<<<dim3(B_), dim3(1024), 0, stream>>>(M, Eo, Ro, U, Bv, XP, walG, outs);
  memsB<<<dim3(B_ * C_), dim3(512), 0, stream>>>(M, Eo, Ro, outs, mems);
}

// Round 17
// 769.673 us; speedup vs baseline: 1.0380x; 1.0380x over previous
//
#include <hip/hip_runtime.h>

#define B_   32
#define T_   512
#define D_   256
#define C_   64
#define R_   4
#define RD_  64
#define OUT_ 256

// ---------------------------------------------------------------------------
__device__ __forceinline__ void bar_lds() {
  asm volatile("s_waitcnt lgkmcnt(0)" ::: "memory");
  __builtin_amdgcn_s_barrier();
  asm volatile("" ::: "memory");
}

// ---- DPP-based wave reductions (VALU pipe) ---------------------------------
template <int CTRL>
__device__ __forceinline__ float dpp_add(float v) {
  int s = __builtin_amdgcn_update_dpp(0, __float_as_int(v), CTRL, 0xF, 0xF, true);
  return v + __int_as_float(s);
}
__device__ __forceinline__ float row16_sum(float v) {
  v = dpp_add<0xB1>(v);   // quad_perm [1,0,3,2]
  v = dpp_add<0x4E>(v);   // quad_perm [2,3,0,1]
  v = dpp_add<0x141>(v);  // row_half_mirror
  v = dpp_add<0x140>(v);  // row_mirror
  return v;
}
__device__ __forceinline__ float rlane(float v, int l) {
  return __int_as_float(__builtin_amdgcn_readlane(__float_as_int(v), l));
}
__device__ __forceinline__ int rlane_i(int v, int l) {
  return __builtin_amdgcn_readlane(v, l);
}
__device__ __forceinline__ float wave_sum_dpp(float v) {
  const float r = row16_sum(v);
  return (rlane(r, 0) + rlane(r, 16)) + (rlane(r, 32) + rlane(r, 48));
}

// ---------------------------------------------------------------------------
// prepK: fused {attnK | xpre} (role split by blockIdx).
//  blocks [0, B*T/4):      attention weights + aggs, one wave per (b,t)
//  blocks [B*T/4, +B*T/32): Xpre = X @ W tile (32 rows x 256 cols)
__global__ __launch_bounds__(256) void prepK(
    const float* __restrict__ X, const float* __restrict__ W,
    const int* __restrict__ Ri, const int* __restrict__ Ei,
    const float* __restrict__ Watt, float* __restrict__ XP,
    float* __restrict__ walG, float* __restrict__ aggs) {
  __shared__ __align__(16) float xs[32][D_];
  const int bid = blockIdx.x;
  if (bid < B_ * T_ / 4) {
    // ---- attnK role ----
    const int wv = threadIdx.x >> 6;
    const int lane = threadIdx.x & 63;
    const size_t bt = (size_t)bid * 4 + wv;
    const int r4 = lane >> 4, seg = lane & 15;

    float y = 0.f;
#pragma unroll
    for (int q = 0; q < 4; ++q) {
      const float4 wt = *(const float4*)&Watt[(r4 << 8) + (seg << 4) + (q << 2)];
      const float4 xv = *(const float4*)&X[bt * D_ + (seg << 4) + (q << 2)];
      y = fmaf(xv.x, wt.x, y);
      y = fmaf(xv.y, wt.y, y);
      y = fmaf(xv.z, wt.z, y);
      y = fmaf(xv.w, wt.w, y);
    }
    y = row16_sum(y);
    const float y0 = rlane(y, 0), y1 = rlane(y, 16);
    const float y2 = rlane(y, 32), y3 = rlane(y, 48);
    const int ric = Ri[bt * C_ + lane];
    const float eic = (float)Ei[bt * C_ + lane];
    float yv = (ric & 1) ? y1 : y0;
    const float yw = (ric & 1) ? y3 : y2;
    yv = (ric & 2) ? yw : yv;
    const float am = __expf(yv) * eic;  // EPS=1e-100 underflows in f32
    const float tot = wave_sum_dpp(am);
    const float alpha = __fdividef(am, tot);

    const float w0 = (ric == 0) ? alpha : 0.f;
    const float w1 = (ric == 1) ? alpha : 0.f;
    const float w2 = (ric == 2) ? alpha : 0.f;
    const float w3 = (ric == 3) ? alpha : 0.f;
    walG[bt * 256 + 0 * C_ + lane] = w0;
    walG[bt * 256 + 1 * C_ + lane] = w1;
    walG[bt * 256 + 2 * C_ + lane] = w2;
    walG[bt * 256 + 3 * C_ + lane] = w3;
    const float s0 = wave_sum_dpp(w0);
    const float s1 = wave_sum_dpp(w1);
    const float s2 = wave_sum_dpp(w2);
    const float s3 = wave_sum_dpp(w3);
    if (lane == 0) {
      float4 v = {s0, s1, s2, s3};
      *(float4*)&aggs[bt * R_] = v;
    }
  } else {
    // ---- xpre role ----
    const int j = threadIdx.x;
    const int row0 = (bid - B_ * T_ / 4) * 32;
    for (int k = 0; k < 32; ++k)
      xs[k][j] = X[(size_t)(row0 + k) * D_ + j];
    __syncthreads();
    float acc[32];
#pragma unroll
    for (int k = 0; k < 32; ++k) acc[k] = 0.f;
    for (int d4 = 0; d4 < D_ / 4; ++d4) {
      const float w0 = W[(d4 * 4 + 0) * OUT_ + j];
      const float w1 = W[(d4 * 4 + 1) * OUT_ + j];
      const float w2 = W[(d4 * 4 + 2) * OUT_ + j];
      const float w3 = W[(d4 * 4 + 3) * OUT_ + j];
#pragma unroll
      for (int k = 0; k < 32; ++k) {
        const float4 x4 = *(const float4*)&xs[k][d4 * 4];
        acc[k] = fmaf(x4.x, w0, fmaf(x4.y, w1, fmaf(x4.z, w2, fmaf(x4.w, w3, acc[k]))));
      }
    }
    for (int k = 0; k < 32; ++k)
      XP[(size_t)(row0 + k) * OUT_ + j] = acc[k];
  }
}

// ---------------------------------------------------------------------------
// gruA: recurrent core. 32 blocks x 1024 threads (16 waves, 4 waves/SIMD).
// Round-15 validated structure (3 barriers/step) + optional mems span-writes:
// if memsW != nullptr, each step's post-update state mt(k) is written to
// mems rows [t_k, t_next) directly from registers (memsB then not needed).
//  A : wave w owns c in [4w,4w+4): mtreg[4]; 16 RL + 16 FMA -> shp[w][r*64+d]
//  B1: prevX at kidx=16w+(lane&15) (16 bcast reads); h2h over K-range
//      [16w,16w+16): 16 RL : 64 FMA with ureg[64]; shprev stash
//  B2: (waves 0-3) h2h = 16-way pBred sum; gates; hnew; all: reload k+2
//  C : mtreg select-update (4 RL) | outs copy-span (waves 8-15) |
//      mems span-writes (all waves, fire-and-forget)
__global__ __launch_bounds__(1024, 4) void gruA(
    const int* __restrict__ M, const int* __restrict__ Eo,
    const int* __restrict__ Ro, const float* __restrict__ U,
    const float* __restrict__ Bv, const float* __restrict__ XP,
    const float* __restrict__ walG, float* __restrict__ outs,
    float* __restrict__ memsW) {
  __shared__ __align__(16) float shp[16][256];    // [wave][r*64+d] prev partials
  __shared__ __align__(16) float pBred[16][256];  // [wave][j] h2h partials
  __shared__ __align__(16) float shprev[OUT_];    // prev[j]
  __shared__ __align__(16) float sh_hnew[OUT_];
  __shared__ int sh_tl[T_];
  __shared__ int sh_nT;

  const int tid = threadIdx.x;
  const int lane = tid & 63;
  const int w = tid >> 6;      // 0..15
  const int b = blockIdx.x;
  const size_t bt0 = (size_t)b * T_;

  // U slice: ureg[jj*16+i] = U[16w+i][jj*64+lane]  (K-range 16 per wave)
  float ureg[64];
#pragma unroll
  for (int jj = 0; jj < 4; ++jj)
#pragma unroll
    for (int i = 0; i < 16; ++i)
      ureg[(jj << 4) + i] = U[(size_t)((w << 4) + i) * OUT_ + (jj << 6) + lane];
  const float breg = Bv[tid & 255];  // used by waves 0-3

  // m state: mtreg[q] = mt[4w+q][lane], init 0
  float mtreg[4];
#pragma unroll
  for (int q = 0; q < 4; ++q) mtreg[q] = 0.f;

  // tlist: indices of m=1 steps (wave 0, ballot prefix scan)
  if (tid < 64) {
    int base = 0;
    for (int ch = 0; ch < 8; ++ch) {
      const int mv = M[bt0 + (ch << 6) + lane];
      const unsigned long long mask = __ballot(mv != 0);
      if (mv) {
        const unsigned long long lt = ((lane == 63) ? ~0ull : ((1ull << (lane + 1)) - 1)) >> 1;
        sh_tl[base + __popcll(mask & lt)] = (ch << 6) + lane;
      }
      base += __popcll(mask);
    }
    if (lane == 0) sh_nT = base;
  }
  __syncthreads();
  const int nT = sh_nT;

  // zero-prefix: outs rows [0, t_0) are h0 = 0; mems rows [0, t_0) are 0
  {
    const int t0 = (nT > 0) ? sh_tl[0] : T_;
    const int j = tid & 255;
    for (int t = tid >> 8; t < t0; t += 4)
      outs[(bt0 + t) * OUT_ + j] = 0.f;
    if (memsW) {
      const int cbase = w << 2;
      for (int t = 0; t < t0; ++t) {
        float* rp = memsW + ((bt0 + t) * (size_t)C_ + cbase) * RD_ + lane;
        rp[0 * RD_] = 0.f;
        rp[1 * RD_] = 0.f;
        rp[2 * RD_] = 0.f;
        rp[3 * RD_] = 0.f;
      }
    }
  }
  if (nT == 0) return;

  // parity register sets:
  //  walS : wal[r = lane&3][c = 4w + (lane>>4)]   (A: readlane at (q<<4)+r)
  //  xpS  : XP[., tid]  (waves 0-3 only)
  //  reS  : Ro | (Eo<<8) at c = 4w + (lane&3)     (C: readlane at q)
  const int cwal = (w << 2) + (lane >> 4);
  const int rwal = lane & 3;
  const int croeo = (w << 2) + (lane & 3);
  float walS0 = 0.f, xpS0 = 0.f, walS1 = 0.f, xpS1 = 0.f;
  int reS0 = 0, reS1 = 0;
  {
    const int t0 = sh_tl[0];
    walS0 = walG[(bt0 + t0) * 256 + (rwal << 6) + cwal];
    if (w < 4) xpS0 = XP[(bt0 + t0) * 256 + tid];
    reS0 = Ro[(bt0 + t0) * C_ + croeo] | (Eo[(bt0 + t0) * C_ + croeo] << 8);
  }
  if (nT > 1) {
    const int t1 = sh_tl[1];
    walS1 = walG[(bt0 + t1) * 256 + (rwal << 6) + cwal];
    if (w < 4) xpS1 = XP[(bt0 + t1) * 256 + tid];
    reS1 = Ro[(bt0 + t1) * C_ + croeo] | (Eo[(bt0 + t1) * C_ + croeo] << 8);
  }

  auto do_step = [&](int k, float& walS, float& xpS, int& reS) {
    const int tk = sh_tl[k];
    const size_t bt = bt0 + tk;
    const int reC = reS;  // consume before the k+2 reload overwrites

    // ---- A: prev partials from mtreg (16 RL + 16 FMA) -> shp ----
    float a0 = 0.f, a1 = 0.f, a2 = 0.f, a3 = 0.f;
#pragma unroll
    for (int q = 0; q < 4; ++q) {
      const float mq = mtreg[q];
      a0 = fmaf(rlane(walS, (q << 4) + 0), mq, a0);
      a1 = fmaf(rlane(walS, (q << 4) + 1), mq, a1);
      a2 = fmaf(rlane(walS, (q << 4) + 2), mq, a2);
      a3 = fmaf(rlane(walS, (q << 4) + 3), mq, a3);
    }
    shp[w][0 * 64 + lane] = a0;
    shp[w][1 * 64 + lane] = a1;
    shp[w][2 * 64 + lane] = a2;
    shp[w][3 * 64 + lane] = a3;
    bar_lds();

    // ---- B1: prevX at kidx (16 bcast reads); h2h partials (16 RL:64 FMA) ----
    const int kidx = (w << 4) + (lane & 15);
    float px = 0.f;
#pragma unroll
    for (int sw = 0; sw < 16; sw += 4) {
      const float t0 = shp[sw + 0][kidx], t1 = shp[sw + 1][kidx];
      const float t2 = shp[sw + 2][kidx], t3 = shp[sw + 3][kidx];
      px += (t0 + t1) + (t2 + t3);
    }
    if (lane < 16) shprev[kidx] = px;
    float p0 = 0.f, p1 = 0.f, p2 = 0.f, p3 = 0.f;
#pragma unroll
    for (int i = 0; i < 16; ++i) {
      const float pk = rlane(px, i);  // prev[16w + i], wave-uniform
      p0 = fmaf(pk, ureg[i], p0);
      p1 = fmaf(pk, ureg[16 + i], p1);
      p2 = fmaf(pk, ureg[32 + i], p2);
      p3 = fmaf(pk, ureg[48 + i], p3);
    }
    pBred[w][0 * 64 + lane] = p0;
    pBred[w][1 * 64 + lane] = p1;
    pBred[w][2 * 64 + lane] = p2;
    pBred[w][3 * 64 + lane] = p3;
    bar_lds();

    // ---- B2: gates on waves 0-3; reload parity set for t_{k+2} (all) ----
    if (w < 4) {
      float h2h = 0.f;
#pragma unroll
      for (int kw = 0; kw < 16; kw += 4) {
        const float t0 = pBred[kw + 0][tid], t1 = pBred[kw + 1][tid];
        const float t2 = pBred[kw + 2][tid], t3 = pBred[kw + 3][tid];
        h2h += (t0 + t1) + (t2 + t3);
      }
      const float pOwn = shprev[tid];
      const float g1 = xpS + h2h + breg;
      const float rg = 1.f / (1.f + __expf(-g1));
      const float targ = xpS + rg * h2h + breg;
      const float e2 = __expf(2.f * targ);
      const float ht = 1.f - 2.f / (e2 + 1.f);  // tanh
      const float hn = (1.f - rg) * pOwn + rg * ht;
      sh_hnew[tid] = hn;
      outs[bt * OUT_ + tid] = hn;
    }
    if (k + 2 < nT) {
      const int t2 = sh_tl[k + 2];
      walS = walG[(bt0 + t2) * 256 + (rwal << 6) + cwal];
      if (w < 4) xpS = XP[(bt0 + t2) * 256 + tid];
      reS = Ro[(bt0 + t2) * C_ + croeo] | (Eo[(bt0 + t2) * C_ + croeo] << 8);
    }
    bar_lds();

    // ---- C: mtreg select-update (4 RL; hnew via 4 conflict-free b32) |
    // ----    outs copy-span (waves 8-15) | mems span-writes (all waves) ----
    const float h0 = sh_hnew[0 * 64 + lane];
    const float h1 = sh_hnew[1 * 64 + lane];
    const float h2 = sh_hnew[2 * 64 + lane];
    const float h3 = sh_hnew[3 * 64 + lane];
#pragma unroll
    for (int q = 0; q < 4; ++q) {
      const int re = rlane_i(reC, q);   // uniform: ro | eo<<8
      const int ro = re & 0xFF;
      const float ha = (ro & 1) ? h1 : h0;
      const float hb = (ro & 1) ? h3 : h2;
      const float hs = (ro & 2) ? hb : ha;
      mtreg[q] = (re & 0x100) ? hs : mtreg[q];
    }
    const int tnext = (k + 1 < nT) ? sh_tl[k + 1] : T_;
    if (w >= 8) {
      // h(t) = hnew(t_k) for t in (t_k, t_next); sh_hnew is stable here
      // (next overwrite is in B2(k+1), two barriers away).
      const int idx = tid - 512;       // 0..511
      const int rr = idx >> 8;         // 0..1
      const int j = idx & 255;
      const float hv = sh_hnew[j];
      for (int t = tk + 1 + rr; t < tnext; t += 2)
        outs[(bt0 + t) * OUT_ + j] = hv;
    }
    if (memsW) {
      // mems[t] = mt(k) for t in [t_k, t_next) — state after step k,
      // written straight from registers (fire-and-forget).
      const int cbase = w << 2;
      for (int t = tk; t < tnext; ++t) {
        float* rp = memsW + ((bt0 + t) * (size_t)C_ + cbase) * RD_ + lane;
        rp[0 * RD_] = mtreg[0];
        rp[1 * RD_] = mtreg[1];
        rp[2 * RD_] = mtreg[2];
        rp[3 * RD_] = mtreg[3];
      }
    }
    // no barrier: next A writes only shp (its B1 readers are 2 bars back);
    // sh_hnew is next written in B2(k+1), two barriers away.
  };

  for (int k = 0; k < nT; k += 2) {
    do_step(k, walS0, xpS0, reS0);
    if (k + 1 < nT) do_step(k + 1, walS1, xpS1, reS1);
  }
}

// ---------------------------------------------------------------------------
// memsB (fallback when d_ws can't hold walG): mems[b,t,c,:] =
// outs-history(tau)[ro(tau,c)*64+:], tau = last step <= t with M&Eo, else 0.
__global__ __launch_bounds__(512) void memsB(const int* __restrict__ M,
                                             const int* __restrict__ Eo,
                                             const int* __restrict__ Ro,
                                             const float* __restrict__ hbuf,
                                             float* __restrict__ mems) {
  __shared__ int lastA[T_];
  const int tid = threadIdx.x;
  const int b = blockIdx.x >> 6;
  const int c = blockIdx.x & 63;
  const size_t bt0 = (size_t)b * T_;
  {
    const int upd = M[bt0 + tid] & Eo[(bt0 + tid) * C_ + c];
    lastA[tid] = upd ? tid : -1;
  }
  __syncthreads();
  for (int off = 1; off < T_; off <<= 1) {
    const int u = (tid >= off) ? lastA[tid - off] : -1;
    const int v = lastA[tid];
    __syncthreads();
    lastA[tid] = (u > v) ? u : v;
    __syncthreads();
  }
  const int d = tid & 63;
  const int t8 = tid >> 6;
  for (int tt = 0; tt < 64; ++tt) {
    const int t = (tt << 3) + t8;
    const int tau = lastA[t];
    float v = 0.f;
    if (tau >= 0) {
      const int rc = Ro[(bt0 + tau) * C_ + c];
      v = hbuf[(bt0 + tau) * OUT_ + (rc << 6) + d];
    }
    mems[((bt0 + t) * C_ + c) * RD_ + d] = v;
  }
}

// ---------------------------------------------------------------------------
extern "C" void kernel_launch(void* const* d_in, const int* in_sizes, int n_in,
                              void* d_out, int out_size, void* d_ws, size_t ws_size,
                              hipStream_t stream) {
  const float* X = (const float*)d_in[0];
  const int* M = (const int*)d_in[1];
  const int* Ei = (const int*)d_in[2];
  const int* Eo = (const int*)d_in[3];
  const int* Ri = (const int*)d_in[4];
  const int* Ro = (const int*)d_in[5];
  const float* W = (const float*)d_in[6];
  const float* U = (const float*)d_in[7];
  const float* Bv = (const float*)d_in[8];
  const float* Watt = (const float*)d_in[9];

  float* outs = (float*)d_out;
  float* mems = outs + (size_t)B_ * T_ * OUT_;
  float* aggs = mems + (size_t)B_ * T_ * C_ * RD_;

  const size_t XPN = (size_t)B_ * T_ * OUT_;         // 4.19M floats, 16.8 MB
  float* XP = (float*)d_ws;
  const bool big_ws = ws_size >= 2 * XPN * sizeof(float);
  // big path: walG lives in d_ws (no alias with mems) and gruA writes mems
  // directly from registers; small path: round-15 behavior (walG aliases
  // mems scratch, memsB reconstructs mems afterwards).
  float* walG = big_ws ? (XP + XPN) : mems;

  prepK<<<dim3(B_ * T_ / 4 + B_ * T_ / 32), dim3(256), 0, stream>>>(
      X, W, Ri, Ei, Watt, XP, walG, aggs);
  gruA<<<dim3(B_), dim3(1024), 0, stream>>>(M, Eo, Ro, U, Bv, XP, walG, outs,
                                            big_ws ? mems : nullptr);
  if (!big_ws)
    memsB<<<dim3(B_ * C_), dim3(512), 0, stream>>>(M, Eo, Ro, outs, mems);
}

// Round 18
// 743.735 us; speedup vs baseline: 1.0742x; 1.0349x over previous
//
#include <hip/hip_runtime.h>

#define B_   32
#define T_   512
#define D_   256
#define C_   64
#define R_   4
#define RD_  64
#define OUT_ 256

// ---------------------------------------------------------------------------
__device__ __forceinline__ void bar_lds() {
  asm volatile("s_waitcnt lgkmcnt(0)" ::: "memory");
  __builtin_amdgcn_s_barrier();
  asm volatile("" ::: "memory");
}

// ---- DPP-based wave reductions (VALU pipe) ---------------------------------
template <int CTRL>
__device__ __forceinline__ float dpp_add(float v) {
  int s = __builtin_amdgcn_update_dpp(0, __float_as_int(v), CTRL, 0xF, 0xF, true);
  return v + __int_as_float(s);
}
__device__ __forceinline__ float row16_sum(float v) {
  v = dpp_add<0xB1>(v);   // quad_perm [1,0,3,2]
  v = dpp_add<0x4E>(v);   // quad_perm [2,3,0,1]
  v = dpp_add<0x141>(v);  // row_half_mirror
  v = dpp_add<0x140>(v);  // row_mirror
  return v;
}
__device__ __forceinline__ float rlane(float v, int l) {
  return __int_as_float(__builtin_amdgcn_readlane(__float_as_int(v), l));
}
__device__ __forceinline__ int rlane_i(int v, int l) {
  return __builtin_amdgcn_readlane(v, l);
}
__device__ __forceinline__ float wave_sum_dpp(float v) {
  const float r = row16_sum(v);
  return (rlane(r, 0) + rlane(r, 16)) + (rlane(r, 32) + rlane(r, 48));
}

// ---------------------------------------------------------------------------
// prepK: fused {attnK | xpre} (role split by blockIdx).
//  blocks [0, B*T/4):      attention weights + aggs, one wave per (b,t)
//  blocks [B*T/4, +B*T/32): Xpre = X @ W tile (32 rows x 256 cols)
__global__ __launch_bounds__(256) void prepK(
    const float* __restrict__ X, const float* __restrict__ W,
    const int* __restrict__ Ri, const int* __restrict__ Ei,
    const float* __restrict__ Watt, float* __restrict__ XP,
    float* __restrict__ walG, float* __restrict__ aggs) {
  __shared__ __align__(16) float xs[32][D_];
  const int bid = blockIdx.x;
  if (bid < B_ * T_ / 4) {
    // ---- attnK role ----
    const int wv = threadIdx.x >> 6;
    const int lane = threadIdx.x & 63;
    const size_t bt = (size_t)bid * 4 + wv;
    const int r4 = lane >> 4, seg = lane & 15;

    float y = 0.f;
#pragma unroll
    for (int q = 0; q < 4; ++q) {
      const float4 wt = *(const float4*)&Watt[(r4 << 8) + (seg << 4) + (q << 2)];
      const float4 xv = *(const float4*)&X[bt * D_ + (seg << 4) + (q << 2)];
      y = fmaf(xv.x, wt.x, y);
      y = fmaf(xv.y, wt.y, y);
      y = fmaf(xv.z, wt.z, y);
      y = fmaf(xv.w, wt.w, y);
    }
    y = row16_sum(y);
    const float y0 = rlane(y, 0), y1 = rlane(y, 16);
    const float y2 = rlane(y, 32), y3 = rlane(y, 48);
    const int ric = Ri[bt * C_ + lane];
    const float eic = (float)Ei[bt * C_ + lane];
    float yv = (ric & 1) ? y1 : y0;
    const float yw = (ric & 1) ? y3 : y2;
    yv = (ric & 2) ? yw : yv;
    const float am = __expf(yv) * eic;  // EPS=1e-100 underflows in f32
    const float tot = wave_sum_dpp(am);
    const float alpha = __fdividef(am, tot);

    const float w0 = (ric == 0) ? alpha : 0.f;
    const float w1 = (ric == 1) ? alpha : 0.f;
    const float w2 = (ric == 2) ? alpha : 0.f;
    const float w3 = (ric == 3) ? alpha : 0.f;
    walG[bt * 256 + 0 * C_ + lane] = w0;
    walG[bt * 256 + 1 * C_ + lane] = w1;
    walG[bt * 256 + 2 * C_ + lane] = w2;
    walG[bt * 256 + 3 * C_ + lane] = w3;
    const float s0 = wave_sum_dpp(w0);
    const float s1 = wave_sum_dpp(w1);
    const float s2 = wave_sum_dpp(w2);
    const float s3 = wave_sum_dpp(w3);
    if (lane == 0) {
      float4 v = {s0, s1, s2, s3};
      *(float4*)&aggs[bt * R_] = v;
    }
  } else {
    // ---- xpre role ----
    const int j = threadIdx.x;
    const int row0 = (bid - B_ * T_ / 4) * 32;
    for (int k = 0; k < 32; ++k)
      xs[k][j] = X[(size_t)(row0 + k) * D_ + j];
    __syncthreads();
    float acc[32];
#pragma unroll
    for (int k = 0; k < 32; ++k) acc[k] = 0.f;
    for (int d4 = 0; d4 < D_ / 4; ++d4) {
      const float w0 = W[(d4 * 4 + 0) * OUT_ + j];
      const float w1 = W[(d4 * 4 + 1) * OUT_ + j];
      const float w2 = W[(d4 * 4 + 2) * OUT_ + j];
      const float w3 = W[(d4 * 4 + 3) * OUT_ + j];
#pragma unroll
      for (int k = 0; k < 32; ++k) {
        const float4 x4 = *(const float4*)&xs[k][d4 * 4];
        acc[k] = fmaf(x4.x, w0, fmaf(x4.y, w1, fmaf(x4.z, w2, fmaf(x4.w, w3, acc[k]))));
      }
    }
    for (int k = 0; k < 32; ++k)
      XP[(size_t)(row0 + k) * OUT_ + j] = acc[k];
  }
}

// ---------------------------------------------------------------------------
// gruA: recurrent core. 32 blocks x 1024 threads (16 waves, 4 waves/SIMD).
// Round-15 validated structure (3 barriers/step, outs fully written here).
//  A : wave w owns c in [4w,4w+4): mtreg[4]; 16 RL + 16 FMA -> shp[w][r*64+d]
//  B1: prevX at kidx=16w+(lane&15) (16 bcast reads); h2h over K-range
//      [16w,16w+16): 16 RL : 64 FMA with ureg[64]; shprev stash
//  B2: (waves 0-3) h2h = 16-way pBred sum; gates; hnew; all: reload k+2
//  C : mtreg select-update (4 RL) | outs copy-span (waves 8-15)
__global__ __launch_bounds__(1024, 4) void gruA(
    const int* __restrict__ M, const int* __restrict__ Eo,
    const int* __restrict__ Ro, const float* __restrict__ U,
    const float* __restrict__ Bv, const float* __restrict__ XP,
    const float* __restrict__ walG, float* __restrict__ outs) {
  __shared__ __align__(16) float shp[16][256];    // [wave][r*64+d] prev partials
  __shared__ __align__(16) float pBred[16][256];  // [wave][j] h2h partials
  __shared__ __align__(16) float shprev[OUT_];    // prev[j]
  __shared__ __align__(16) float sh_hnew[OUT_];
  __shared__ int sh_tl[T_];
  __shared__ int sh_nT;

  const int tid = threadIdx.x;
  const int lane = tid & 63;
  const int w = tid >> 6;      // 0..15
  const int b = blockIdx.x;
  const size_t bt0 = (size_t)b * T_;

  // U slice: ureg[jj*16+i] = U[16w+i][jj*64+lane]  (K-range 16 per wave)
  float ureg[64];
#pragma unroll
  for (int jj = 0; jj < 4; ++jj)
#pragma unroll
    for (int i = 0; i < 16; ++i)
      ureg[(jj << 4) + i] = U[(size_t)((w << 4) + i) * OUT_ + (jj << 6) + lane];
  const float breg = Bv[tid & 255];  // used by waves 0-3

  // m state: mtreg[q] = mt[4w+q][lane], init 0
  float mtreg[4];
#pragma unroll
  for (int q = 0; q < 4; ++q) mtreg[q] = 0.f;

  // tlist: indices of m=1 steps (wave 0, ballot prefix scan)
  if (tid < 64) {
    int base = 0;
    for (int ch = 0; ch < 8; ++ch) {
      const int mv = M[bt0 + (ch << 6) + lane];
      const unsigned long long mask = __ballot(mv != 0);
      if (mv) {
        const unsigned long long lt = ((lane == 63) ? ~0ull : ((1ull << (lane + 1)) - 1)) >> 1;
        sh_tl[base + __popcll(mask & lt)] = (ch << 6) + lane;
      }
      base += __popcll(mask);
    }
    if (lane == 0) sh_nT = base;
  }
  __syncthreads();
  const int nT = sh_nT;

  // zero-prefix: outs rows [0, t_0) are h0 = 0 (all rows if nT == 0)
  {
    const int t0 = (nT > 0) ? sh_tl[0] : T_;
    const int j = tid & 255;
    for (int t = tid >> 8; t < t0; t += 4)
      outs[(bt0 + t) * OUT_ + j] = 0.f;
  }
  if (nT == 0) return;

  // parity register sets:
  //  walS : wal[r = lane&3][c = 4w + (lane>>4)]   (A: readlane at (q<<4)+r)
  //  xpS  : XP[., tid]  (waves 0-3 only)
  //  reS  : Ro | (Eo<<8) at c = 4w + (lane&3)     (C: readlane at q)
  const int cwal = (w << 2) + (lane >> 4);
  const int rwal = lane & 3;
  const int croeo = (w << 2) + (lane & 3);
  float walS0 = 0.f, xpS0 = 0.f, walS1 = 0.f, xpS1 = 0.f;
  int reS0 = 0, reS1 = 0;
  {
    const int t0 = sh_tl[0];
    walS0 = walG[(bt0 + t0) * 256 + (rwal << 6) + cwal];
    if (w < 4) xpS0 = XP[(bt0 + t0) * 256 + tid];
    reS0 = Ro[(bt0 + t0) * C_ + croeo] | (Eo[(bt0 + t0) * C_ + croeo] << 8);
  }
  if (nT > 1) {
    const int t1 = sh_tl[1];
    walS1 = walG[(bt0 + t1) * 256 + (rwal << 6) + cwal];
    if (w < 4) xpS1 = XP[(bt0 + t1) * 256 + tid];
    reS1 = Ro[(bt0 + t1) * C_ + croeo] | (Eo[(bt0 + t1) * C_ + croeo] << 8);
  }

  auto do_step = [&](int k, float& walS, float& xpS, int& reS) {
    const int tk = sh_tl[k];
    const size_t bt = bt0 + tk;
    const int reC = reS;  // consume before the k+2 reload overwrites

    // ---- A: prev partials from mtreg (16 RL + 16 FMA) -> shp ----
    float a0 = 0.f, a1 = 0.f, a2 = 0.f, a3 = 0.f;
#pragma unroll
    for (int q = 0; q < 4; ++q) {
      const float mq = mtreg[q];
      a0 = fmaf(rlane(walS, (q << 4) + 0), mq, a0);
      a1 = fmaf(rlane(walS, (q << 4) + 1), mq, a1);
      a2 = fmaf(rlane(walS, (q << 4) + 2), mq, a2);
      a3 = fmaf(rlane(walS, (q << 4) + 3), mq, a3);
    }
    shp[w][0 * 64 + lane] = a0;
    shp[w][1 * 64 + lane] = a1;
    shp[w][2 * 64 + lane] = a2;
    shp[w][3 * 64 + lane] = a3;
    bar_lds();

    // ---- B1: prevX at kidx (16 bcast reads); h2h partials (16 RL:64 FMA) ----
    const int kidx = (w << 4) + (lane & 15);
    float px = 0.f;
#pragma unroll
    for (int sw = 0; sw < 16; sw += 4) {
      const float t0 = shp[sw + 0][kidx], t1 = shp[sw + 1][kidx];
      const float t2 = shp[sw + 2][kidx], t3 = shp[sw + 3][kidx];
      px += (t0 + t1) + (t2 + t3);
    }
    if (lane < 16) shprev[kidx] = px;
    float p0 = 0.f, p1 = 0.f, p2 = 0.f, p3 = 0.f;
#pragma unroll
    for (int i = 0; i < 16; ++i) {
      const float pk = rlane(px, i);  // prev[16w + i], wave-uniform
      p0 = fmaf(pk, ureg[i], p0);
      p1 = fmaf(pk, ureg[16 + i], p1);
      p2 = fmaf(pk, ureg[32 + i], p2);
      p3 = fmaf(pk, ureg[48 + i], p3);
    }
    pBred[w][0 * 64 + lane] = p0;
    pBred[w][1 * 64 + lane] = p1;
    pBred[w][2 * 64 + lane] = p2;
    pBred[w][3 * 64 + lane] = p3;
    bar_lds();

    // ---- B2: gates on waves 0-3; reload parity set for t_{k+2} (all) ----
    if (w < 4) {
      float h2h = 0.f;
#pragma unroll
      for (int kw = 0; kw < 16; kw += 4) {
        const float t0 = pBred[kw + 0][tid], t1 = pBred[kw + 1][tid];
        const float t2 = pBred[kw + 2][tid], t3 = pBred[kw + 3][tid];
        h2h += (t0 + t1) + (t2 + t3);
      }
      const float pOwn = shprev[tid];
      const float g1 = xpS + h2h + breg;
      const float rg = 1.f / (1.f + __expf(-g1));
      const float targ = xpS + rg * h2h + breg;
      const float e2 = __expf(2.f * targ);
      const float ht = 1.f - 2.f / (e2 + 1.f);  // tanh
      const float hn = (1.f - rg) * pOwn + rg * ht;
      sh_hnew[tid] = hn;
      outs[bt * OUT_ + tid] = hn;
    }
    if (k + 2 < nT) {
      const int t2 = sh_tl[k + 2];
      walS = walG[(bt0 + t2) * 256 + (rwal << 6) + cwal];
      if (w < 4) xpS = XP[(bt0 + t2) * 256 + tid];
      reS = Ro[(bt0 + t2) * C_ + croeo] | (Eo[(bt0 + t2) * C_ + croeo] << 8);
    }
    bar_lds();

    // ---- C: mtreg select-update (4 RL; hnew via 4 conflict-free b32) |
    // ----    outs copy-span rows (t_k, t_next) on waves 8-15 --------------
    const float h0 = sh_hnew[0 * 64 + lane];
    const float h1 = sh_hnew[1 * 64 + lane];
    const float h2 = sh_hnew[2 * 64 + lane];
    const float h3 = sh_hnew[3 * 64 + lane];
#pragma unroll
    for (int q = 0; q < 4; ++q) {
      const int re = rlane_i(reC, q);   // uniform: ro | eo<<8
      const int ro = re & 0xFF;
      const float ha = (ro & 1) ? h1 : h0;
      const float hb = (ro & 1) ? h3 : h2;
      const float hs = (ro & 2) ? hb : ha;
      mtreg[q] = (re & 0x100) ? hs : mtreg[q];
    }
    if (w >= 8) {
      // h(t) = hnew(t_k) for t in (t_k, t_next); sh_hnew is stable here
      // (next overwrite is in B2(k+1), two barriers away).
      const int idx = tid - 512;       // 0..511
      const int rr = idx >> 8;         // 0..1
      const int j = idx & 255;
      const int tnext = (k + 1 < nT) ? sh_tl[k + 1] : T_;
      const float hv = sh_hnew[j];
      for (int t = tk + 1 + rr; t < tnext; t += 2)
        outs[(bt0 + t) * OUT_ + j] = hv;
    }
    // no barrier: next A writes only shp (its B1 readers are 2 bars back);
    // sh_hnew is next written in B2(k+1), two barriers away.
  };

  for (int k = 0; k < nT; k += 2) {
    do_step(k, walS0, xpS0, reS0);
    if (k + 1 < nT) do_step(k + 1, walS1, xpS1, reS1);
  }
}

// ---------------------------------------------------------------------------
// memsB: mems[b,t,c,:] = outs-history(tau)[ro(tau,c)*64+:], tau = last step
// <= t with M&Eo, else 0. Rows at M=1 steps hold true hnew (gruA). One block
// per (b,c).
__global__ __launch_bounds__(512) void memsB(const int* __restrict__ M,
                                             const int* __restrict__ Eo,
                                             const int* __restrict__ Ro,
                                             const float* __restrict__ hbuf,
                                             float* __restrict__ mems) {
  __shared__ int lastA[T_];
  const int tid = threadIdx.x;
  const int b = blockIdx.x >> 6;
  const int c = blockIdx.x & 63;
  const size_t bt0 = (size_t)b * T_;
  {
    const int upd = M[bt0 + tid] & Eo[(bt0 + tid) * C_ + c];
    lastA[tid] = upd ? tid : -1;
  }
  __syncthreads();
  for (int off = 1; off < T_; off <<= 1) {
    const int u = (tid >= off) ? lastA[tid - off] : -1;
    const int v = lastA[tid];
    __syncthreads();
    lastA[tid] = (u > v) ? u : v;
    __syncthreads();
  }
  const int d = tid & 63;
  const int t8 = tid >> 6;
  for (int tt = 0; tt < 64; ++tt) {
    const int t = (tt << 3) + t8;
    const int tau = lastA[t];
    float v = 0.f;
    if (tau >= 0) {
      const int rc = Ro[(bt0 + tau) * C_ + c];
      v = hbuf[(bt0 + tau) * OUT_ + (rc << 6) + d];
    }
    mems[((bt0 + t) * C_ + c) * RD_ + d] = v;
  }
}

// ---------------------------------------------------------------------------
extern "C" void kernel_launch(void* const* d_in, const int* in_sizes, int n_in,
                              void* d_out, int out_size, void* d_ws, size_t ws_size,
                              hipStream_t stream) {
  const float* X = (const float*)d_in[0];
  const int* M = (const int*)d_in[1];
  const int* Ei = (const int*)d_in[2];
  const int* Eo = (const int*)d_in[3];
  const int* Ri = (const int*)d_in[4];
  const int* Ro = (const int*)d_in[5];
  const float* W = (const float*)d_in[6];
  const float* U = (const float*)d_in[7];
  const float* Bv = (const float*)d_in[8];
  const float* Watt = (const float*)d_in[9];

  float* outs = (float*)d_out;
  float* mems = outs + (size_t)B_ * T_ * OUT_;
  float* aggs = mems + (size_t)B_ * T_ * C_ * RD_;
  float* XP = (float*)d_ws;   // 16.8 MB scratch
  float* walG = mems;         // alpha scratch aliases mems (memsB overwrites)

  prepK<<<dim3(B_ * T_ / 4 + B_ * T_ / 32), dim3(256), 0, stream>>>(
      X, W, Ri, Ei, Watt, XP, walG, aggs);
  gruA<<<dim3(B_), dim3(1024), 0, stream>>>(M, Eo, Ro, U, Bv, XP, walG, outs);
  memsB<<<dim3(B_ * C_), dim3(512), 0, stream>>>(M, Eo, Ro, outs, mems);
}